// Round 1
// baseline (87.333 us; speedup 1.0000x reference)
//
#include <hip/hip_runtime.h>
#include <hip/hip_fp16.h>

// ---------------------------------------------------------------------------
// DotProductAttention: O = softmax((Q K^T / sqrt(128)) * p_q * p_k^T) V
// B=16, S=2048, D=128, fp32 in/out.
// Strategy: fold scale*p_q into Q, p_k into K (exact rank-1 folds), cast to
// fp16, run flash-attention with swapped-QK^T 32x32x16 MFMAs.
// Pre-pass kernels write LDS-image (pre-swizzled) fp16 copies of K and V so
// the main kernel stages tiles with linear global_load_lds (16B).
// ---------------------------------------------------------------------------

typedef _Float16 f16x8 __attribute__((ext_vector_type(8)));
typedef float f32x16 __attribute__((ext_vector_type(16)));
typedef unsigned int u32x4 __attribute__((ext_vector_type(4)));

#define S_LEN 2048
#define NBATCH 16
#define DD 128
#define TILE_BYTES 16384   // 64 keys x 128 d x 2B (one image tile)
#define NT 32              // kv tiles of 64 keys

__device__ __forceinline__ unsigned int pk2(float a, float b) {
  __half2 h = __float22half2_rn(make_float2(a, b));
  return __builtin_bit_cast(unsigned int, h);
}

__device__ __forceinline__ void st8(void* dst, const float v[8]) {
  u32x4 u;
  u[0] = pk2(v[0], v[1]);
  u[1] = pk2(v[2], v[3]);
  u[2] = pk2(v[4], v[5]);
  u[3] = pk2(v[6], v[7]);
  *(u32x4*)dst = u;
}

__device__ __forceinline__ void gld16(const void* g, void* l) {
  __builtin_amdgcn_global_load_lds(
      (const __attribute__((address_space(1))) unsigned int*)g,
      (__attribute__((address_space(3))) unsigned int*)l, 16, 0, 0);
}

// --------------------------- pre-pass: Q --------------------------------
// Q' = fp16(Q * (1/sqrt(128)) * p_q[row]); row-major [B*S][128]
__global__ __launch_bounds__(256) void prep_q_k(const float* __restrict__ Q,
                                                const float* __restrict__ pq,
                                                char* __restrict__ qh) {
  size_t i = ((size_t)blockIdx.x * 256 + threadIdx.x) * 8;
  const float g = pq[i >> 7] * 0.08838834764831845f;
  float4 a = *(const float4*)(Q + i);
  float4 b = *(const float4*)(Q + i + 4);
  float v[8] = {a.x * g, a.y * g, a.z * g, a.w * g,
                b.x * g, b.y * g, b.z * g, b.w * g};
  st8(qh + i * 2, v);
}

// --------------------------- pre-pass: K,V images ------------------------
// K image tile (64x128): byte(key,d) = key*256 + ((2d) ^ ((key&7)<<4))
//   (row-major + XOR bank swizzle; K is gated by p_k[key])
// V image tile:          byte(key,d) = d*128 + ((2key) ^ ((d&7)<<4))
//   (d-major "V^T rows" + XOR bank swizzle)
__global__ __launch_bounds__(256) void prep_kv(
    const float* __restrict__ K, const float* __restrict__ V,
    const float* __restrict__ pk, char* __restrict__ kimg,
    char* __restrict__ vimg) {
  __shared__ float vt[64 * 132];
  const int t = threadIdx.x;
  const int bid = blockIdx.x;
  const int bq = bid & 15;
  const int kt = bid >> 4;
  const size_t rowbase = (size_t)bq * S_LEN + kt * 64;

  // stage V tile (fp32) into padded LDS for the transpose
#pragma unroll
  for (int cc = 0; cc < 8; ++cc) {
    const int f = cc * 256 + t;
    const int row = f >> 5;
    const int col = (f & 31) * 4;
    *(float4*)(vt + row * 132 + col) = *(const float4*)(V + (rowbase + row) * DD + col);
  }

  // K image: pure global->global, fold p_k
  char* kdst = kimg + (size_t)(bq * NT + kt) * TILE_BYTES;
#pragma unroll
  for (int cc = 0; cc < 4; ++cc) {
    const int p0 = (cc * 256 + t) * 16;
    const int key = p0 >> 8;
    const int d0 = ((p0 & 255) ^ ((key & 7) << 4)) >> 1;
    const float g = pk[rowbase + key];
    const float* src = K + (rowbase + key) * DD + d0;
    float4 a = *(const float4*)(src);
    float4 b = *(const float4*)(src + 4);
    float v[8] = {a.x * g, a.y * g, a.z * g, a.w * g,
                  b.x * g, b.y * g, b.z * g, b.w * g};
    st8(kdst + p0, v);
  }

  __syncthreads();

  // V image from LDS transpose
  char* vdst = vimg + (size_t)(bq * NT + kt) * TILE_BYTES;
#pragma unroll
  for (int cc = 0; cc < 4; ++cc) {
    const int p0 = (cc * 256 + t) * 16;
    const int dcol = p0 >> 7;
    const int key0 = ((p0 & 127) ^ ((dcol & 7) << 4)) >> 1;
    float v[8];
#pragma unroll
    for (int j = 0; j < 8; ++j) v[j] = vt[(key0 + j) * 132 + dcol];
    st8(vdst + p0, v);
  }
}

// --------------------------- main attention ------------------------------
// 2 waves x 32 q-rows per block; KVBLK=64; swapped QK^T (mfma(K,Q) -> S^T):
//   S^T lane layout: q = lane&31 (lane-local softmax row), key5 = (r&3)+8*(r>>2)+4h
// PV computes O^T = mfma(V^T, P^T); P^T fragments built in-register with one
// xor-32 exchange. Final O^T->O transpose through LDS.
__global__ __launch_bounds__(128) void attn_main(const char* __restrict__ qh,
                                                 const char* __restrict__ kimg,
                                                 const char* __restrict__ vimg,
                                                 float* __restrict__ out) {
  __shared__ float4 ldsraw[4096];  // 64 KB: two 32KB buffers (K 16K + V 16K each)
  char* lds = (char*)ldsraw;
  const int tid = threadIdx.x;
  const int wq = tid >> 6;
  const int lane = tid & 63;
  const int c = lane & 31;
  const int h = lane >> 5;
  const int swz = (c & 7) << 4;
  const int bid = blockIdx.x;
  const int bq = bid & 15;   // batch pinned to XCD (bid%8) for L2 locality
  const int qt = bid >> 4;
  const int q0 = qt * 64 + wq * 32;

  // Q fragments (B-operand of swapped QK^T): lane c = q row, 8 d's per kc
  f16x8 qf[8];
  const char* qrow = qh + (size_t)(bq * S_LEN + q0 + c) * (DD * 2);
#pragma unroll
  for (int kc = 0; kc < 8; ++kc) qf[kc] = *(const f16x8*)(qrow + kc * 32 + h * 16);

  f32x16 acc[4];
#pragma unroll
  for (int d = 0; d < 4; ++d) {
#pragma unroll
    for (int r = 0; r < 16; ++r) acc[d][r] = 0.f;
  }
  float m_run = -3.0e38f, l_run = 0.f;

  const char* kb = kimg + (size_t)bq * (NT * TILE_BYTES);
  const char* vb = vimg + (size_t)bq * (NT * TILE_BYTES);

  // prologue: stage tile 0 into buffer 0 (linear copy of pre-swizzled image)
#pragma unroll
  for (int j = 0; j < 8; ++j) {
    gld16(kb + j * 2048 + tid * 16, lds + j * 2048 + tid * 16);
    gld16(vb + j * 2048 + tid * 16, lds + TILE_BYTES + j * 2048 + tid * 16);
  }

  for (int kt = 0; kt < NT; ++kt) {
    __syncthreads();  // drains staging vmcnt; frees other buffer
    const int cur = (kt & 1) * 32768;
    if (kt + 1 < NT) {
      const int nxt = ((kt + 1) & 1) * 32768;
      const char* kn = kb + (size_t)(kt + 1) * TILE_BYTES;
      const char* vn = vb + (size_t)(kt + 1) * TILE_BYTES;
#pragma unroll
      for (int j = 0; j < 8; ++j) {
        gld16(kn + j * 2048 + tid * 16, lds + nxt + j * 2048 + tid * 16);
        gld16(vn + j * 2048 + tid * 16, lds + nxt + TILE_BYTES + j * 2048 + tid * 16);
      }
    }
    const char* kl = lds + cur;
    const char* vl = lds + cur + TILE_BYTES;

    // S^T = K' Q'^T  (two 32-key subtiles)
    f32x16 s0, s1;
#pragma unroll
    for (int r = 0; r < 16; ++r) { s0[r] = 0.f; s1[r] = 0.f; }
#pragma unroll
    for (int kc = 0; kc < 8; ++kc) {
      f16x8 k0 = *(const f16x8*)(kl + c * 256 + ((kc * 32 + h * 16) ^ swz));
      f16x8 k1 = *(const f16x8*)(kl + (32 + c) * 256 + ((kc * 32 + h * 16) ^ swz));
      s0 = __builtin_amdgcn_mfma_f32_32x32x16_f16(k0, qf[kc], s0, 0, 0, 0);
      s1 = __builtin_amdgcn_mfma_f32_32x32x16_f16(k1, qf[kc], s1, 0, 0, 0);
    }

    // lane-local online softmax (row q = c); only h-halves need one xor-32
    float cm = fmaxf(s0[0], s1[0]);
#pragma unroll
    for (int r = 1; r < 16; ++r) cm = fmaxf(cm, fmaxf(s0[r], s1[r]));
    cm = fmaxf(cm, __shfl_xor(cm, 32));
    const float mn = fmaxf(m_run, cm);
    const float al = __expf(m_run - mn);
    m_run = mn;
    float ps = 0.f;
#pragma unroll
    for (int r = 0; r < 16; ++r) {
      s0[r] = __expf(s0[r] - mn); ps += s0[r];
      s1[r] = __expf(s1[r] - mn); ps += s1[r];
    }
    l_run = l_run * al + ps;
#pragma unroll
    for (int d = 0; d < 4; ++d) {
#pragma unroll
      for (int r = 0; r < 16; ++r) acc[d][r] *= al;
    }

    // PV: O^T += V^T P^T ; build P^T B-frags in-register (one xor-32 swap)
#pragma unroll
    for (int kc = 0; kc < 4; ++kc) {
      const f32x16 pn = (kc < 2) ? s0 : s1;   // n = kc>>1 (folds at unroll)
      const int A = (kc & 1) * 8;             // reg base for (2kc)&3
      const int Bb = A + 4;                   // reg base for (2kc+1)&3
      unsigned pA0 = pk2(pn[A + 0], pn[A + 1]);
      unsigned pA1 = pk2(pn[A + 2], pn[A + 3]);
      unsigned pB0 = pk2(pn[Bb + 0], pn[Bb + 1]);
      unsigned pB1 = pk2(pn[Bb + 2], pn[Bb + 3]);
      unsigned own0 = h ? pB0 : pA0;
      unsigned own1 = h ? pB1 : pA1;
      unsigned snd0 = h ? pA0 : pB0;
      unsigned snd1 = h ? pA1 : pB1;
      unsigned rcv0 = __shfl_xor(snd0, 32);
      unsigned rcv1 = __shfl_xor(snd1, 32);
      u32x4 pw;
      pw[0] = h ? rcv0 : own0;  // elems 0,1 (source half h=0)
      pw[1] = h ? rcv1 : own1;  // elems 2,3
      pw[2] = h ? own0 : rcv0;  // elems 4,5 (source half h=1)
      pw[3] = h ? own1 : rcv1;  // elems 6,7
      f16x8 pf = __builtin_bit_cast(f16x8, pw);
#pragma unroll
      for (int d = 0; d < 4; ++d) {
        f16x8 vf = *(const f16x8*)(vl + (d * 32 + c) * 128 + ((kc * 32 + h * 16) ^ swz));
        acc[d] = __builtin_amdgcn_mfma_f32_32x32x16_f16(vf, pf, acc[d], 0, 0, 0);
      }
    }
  }

  l_run += __shfl_xor(l_run, 32);
  const float inv = 1.f / l_run;

  __syncthreads();
  // O^T -> O transpose through LDS (per-wave 16KB region in freed buffer 0)
  char* T = lds + wq * 16384;
#pragma unroll
  for (int d = 0; d < 4; ++d) {
#pragma unroll
    for (int rr = 0; rr < 4; ++rr) {
      const int dd = d * 32 + rr * 8 + h * 4;
      float4 v4;
      v4.x = acc[d][rr * 4 + 0] * inv;
      v4.y = acc[d][rr * 4 + 1] * inv;
      v4.z = acc[d][rr * 4 + 2] * inv;
      v4.w = acc[d][rr * 4 + 3] * inv;
      *(float4*)(T + c * 512 + ((dd * 4) ^ swz)) = v4;
    }
  }
  float* orow = out + (size_t)(bq * S_LEN + q0) * DD;
#pragma unroll
  for (int j = 0; j < 16; ++j) {
    const int chunk = j * 64 + lane;
    const int qq = chunk >> 5;
    const int d0 = (chunk & 31) * 4;
    float4 v4 = *(const float4*)(T + qq * 512 + ((d0 * 4) ^ ((qq & 7) << 4)));
    *(float4*)(orow + qq * DD + d0) = v4;
  }
}

// --------------------------- launcher ------------------------------------
extern "C" void kernel_launch(void* const* d_in, const int* in_sizes, int n_in,
                              void* d_out, int out_size, void* d_ws, size_t ws_size,
                              hipStream_t stream) {
  const float* Q = (const float*)d_in[0];
  const float* K = (const float*)d_in[1];
  const float* V = (const float*)d_in[2];
  const float* pq = (const float*)d_in[3];
  const float* pk = (const float*)d_in[4];
  float* out = (float*)d_out;
  char* ws = (char*)d_ws;
  char* qh = ws;                         // 8 MB fp16 scaled Q
  char* kimg = ws + (8u << 20);          // 8 MB K image (gated, swizzled)
  char* vimg = ws + (16u << 20);         // 8 MB V image (transposed, swizzled)

  prep_q_k<<<2048, 256, 0, stream>>>(Q, pq, qh);
  prep_kv<<<512, 256, 0, stream>>>(K, V, pk, kimg, vimg);
  attn_main<<<512, 128, 0, stream>>>(qh, kimg, vimg, out);
}

// Round 3
// 66.334 us; speedup vs baseline: 1.3166x; 1.3166x over previous
//
#include <hip/hip_runtime.h>
#include <hip/hip_fp16.h>

// ---------------------------------------------------------------------------
// DotProductAttention: O = softmax((Q K^T / sqrt(128)) * p_q * p_k^T) V
// B=16, S=2048, D=128, fp32 in/out.
// Fold scale*p_q*log2(e) into Q, p_k into K (exact rank-1 folds), cast fp16,
// flash-attention with swapped-QK^T 32x32x16 MFMAs in log2-softmax domain.
// Round 2: 512-thread blocks (4 q-subtiles x 2 key-halves), grid 256
// -> 8 waves/CU (2/SIMD) for MFMA/VALU overlap; defer-max rescale skip;
// exp2-domain softmax (v_exp_f32 via __builtin_amdgcn_exp2f); setprio
// around MFMA clusters.
// ---------------------------------------------------------------------------

typedef _Float16 f16x8 __attribute__((ext_vector_type(8)));
typedef float f32x16 __attribute__((ext_vector_type(16)));
typedef unsigned int u32x4 __attribute__((ext_vector_type(4)));

#define S_LEN 2048
#define DD 128
#define TILE_BYTES 16384   // 64 keys x 128 d x 2B (one image tile)
#define NT 32              // kv tiles of 64 keys

#define EXP2(x) __builtin_amdgcn_exp2f(x)   // raw v_exp_f32 (2^x)

__device__ __forceinline__ unsigned int pk2(float a, float b) {
  __half2 h = __float22half2_rn(make_float2(a, b));
  return __builtin_bit_cast(unsigned int, h);
}

__device__ __forceinline__ void st8(void* dst, const float v[8]) {
  u32x4 u;
  u[0] = pk2(v[0], v[1]);
  u[1] = pk2(v[2], v[3]);
  u[2] = pk2(v[4], v[5]);
  u[3] = pk2(v[6], v[7]);
  *(u32x4*)dst = u;
}

__device__ __forceinline__ void gld16(const void* g, void* l) {
  __builtin_amdgcn_global_load_lds(
      (const __attribute__((address_space(1))) unsigned int*)g,
      (__attribute__((address_space(3))) unsigned int*)l, 16, 0, 0);
}

// --------------------------- pre-pass: Q --------------------------------
// Q' = fp16(Q * (log2e/sqrt(128)) * p_q[row]); row-major [B*S][128]
// (log2e fold => softmax exp becomes a bare v_exp_f32 (2^x))
__global__ __launch_bounds__(256) void prep_q_k(const float* __restrict__ Q,
                                                const float* __restrict__ pq,
                                                char* __restrict__ qh) {
  size_t i = ((size_t)blockIdx.x * 256 + threadIdx.x) * 8;
  const float g = pq[i >> 7] * 0.12751743343158394f;  // (1/sqrt(128))*log2(e)
  float4 a = *(const float4*)(Q + i);
  float4 b = *(const float4*)(Q + i + 4);
  float v[8] = {a.x * g, a.y * g, a.z * g, a.w * g,
                b.x * g, b.y * g, b.z * g, b.w * g};
  st8(qh + i * 2, v);
}

// --------------------------- pre-pass: K,V images ------------------------
// K image tile (64x128): byte(key,d) = key*256 + ((2d) ^ ((key&7)<<4))
//   (row-major + XOR bank swizzle; K is gated by p_k[key])
// V image tile:          byte(key,d) = d*128 + ((2key) ^ ((d&7)<<4))
//   (d-major "V^T rows" + XOR bank swizzle)
__global__ __launch_bounds__(256) void prep_kv(
    const float* __restrict__ K, const float* __restrict__ V,
    const float* __restrict__ pk, char* __restrict__ kimg,
    char* __restrict__ vimg) {
  __shared__ float vt[64 * 132];
  const int t = threadIdx.x;
  const int bid = blockIdx.x;
  const int bq = bid & 15;
  const int kt = bid >> 4;
  const size_t rowbase = (size_t)bq * S_LEN + kt * 64;

  // stage V tile (fp32) into padded LDS for the transpose
#pragma unroll
  for (int cc = 0; cc < 8; ++cc) {
    const int f = cc * 256 + t;
    const int row = f >> 5;
    const int col = (f & 31) * 4;
    *(float4*)(vt + row * 132 + col) = *(const float4*)(V + (rowbase + row) * DD + col);
  }

  // K image: pure global->global, fold p_k
  char* kdst = kimg + (size_t)(bq * NT + kt) * TILE_BYTES;
#pragma unroll
  for (int cc = 0; cc < 4; ++cc) {
    const int p0 = (cc * 256 + t) * 16;
    const int key = p0 >> 8;
    const int d0 = ((p0 & 255) ^ ((key & 7) << 4)) >> 1;
    const float g = pk[rowbase + key];
    const float* src = K + (rowbase + key) * DD + d0;
    float4 a = *(const float4*)(src);
    float4 b = *(const float4*)(src + 4);
    float v[8] = {a.x * g, a.y * g, a.z * g, a.w * g,
                  b.x * g, b.y * g, b.z * g, b.w * g};
    st8(kdst + p0, v);
  }

  __syncthreads();

  // V image from LDS transpose
  char* vdst = vimg + (size_t)(bq * NT + kt) * TILE_BYTES;
#pragma unroll
  for (int cc = 0; cc < 4; ++cc) {
    const int p0 = (cc * 256 + t) * 16;
    const int dcol = p0 >> 7;
    const int key0 = ((p0 & 127) ^ ((dcol & 7) << 4)) >> 1;
    float v[8];
#pragma unroll
    for (int j = 0; j < 8; ++j) v[j] = vt[(key0 + j) * 132 + dcol];
    st8(vdst + p0, v);
  }
}

// --------------------------- main attention ------------------------------
// 512 threads = 8 waves: wid = qs*2 + ks; qs in [0,4) picks a 32-q subtile,
// ks in {0,1} picks the key-half of each 64-key tile (independent online
// softmax per key-half; partials merged in the epilogue through LDS).
// Swapped QK^T: S^T = mfma(K, Q) -> softmax row q is lane-local (q = lane&31).
// PV: O^T = mfma(V^T, P^T), P^T built in-register with one xor-32 exchange.
__global__ __launch_bounds__(512, 2) void attn_main(const char* __restrict__ qh,
                                                    const char* __restrict__ kimg,
                                                    const char* __restrict__ vimg,
                                                    float* __restrict__ out) {
  __shared__ float4 ldsraw[4352];  // 69632 B: 2x32KB stage buffers + T(64KB alias) + 2KB ml
  char* lds = (char*)ldsraw;
  const int tid = threadIdx.x;
  const int wid = tid >> 6;
  const int qs = wid >> 1;   // q subtile 0..3
  const int ks = wid & 1;    // key half 0..1
  const int lane = tid & 63;
  const int c = lane & 31;
  const int h = lane >> 5;
  const int swz = (c & 7) << 4;
  const int bid = blockIdx.x;
  const int bq = 2 * (bid & 7) + ((bid >> 3) & 1);  // batch pinned to XCD
  const int qt = bid >> 4;
  const int q0 = qt * 128 + qs * 32;

  // Q fragments (B-operand of swapped QK^T): lane c = q row, 8 d's per kc
  f16x8 qf[8];
  const char* qrow = qh + (size_t)(bq * S_LEN + q0 + c) * (DD * 2);
#pragma unroll
  for (int kc = 0; kc < 8; ++kc) qf[kc] = *(const f16x8*)(qrow + kc * 32 + h * 16);

  f32x16 acc[4];
#pragma unroll
  for (int d = 0; d < 4; ++d) {
#pragma unroll
    for (int r = 0; r < 16; ++r) acc[d][r] = 0.f;
  }
  float m_run = -1.0e30f, l_run = 0.f;

  const char* kb = kimg + (size_t)bq * (NT * TILE_BYTES);
  const char* vb = vimg + (size_t)bq * (NT * TILE_BYTES);

  // prologue: stage tile 0 into buffer 0 (linear copy of pre-swizzled image)
#pragma unroll
  for (int j = 0; j < 2; ++j) {
    gld16(kb + j * 8192 + tid * 16, lds + j * 8192 + tid * 16);
    gld16(vb + j * 8192 + tid * 16, lds + TILE_BYTES + j * 8192 + tid * 16);
  }

  for (int kt = 0; kt < NT; ++kt) {
    __syncthreads();  // drains staging vmcnt; frees other buffer
    const int cur = (kt & 1) << 15;
    if (kt + 1 < NT) {
      const int nxt = ((kt + 1) & 1) << 15;
      const char* kn = kb + (size_t)(kt + 1) * TILE_BYTES;
      const char* vn = vb + (size_t)(kt + 1) * TILE_BYTES;
#pragma unroll
      for (int j = 0; j < 2; ++j) {
        gld16(kn + j * 8192 + tid * 16, lds + nxt + j * 8192 + tid * 16);
        gld16(vn + j * 8192 + tid * 16, lds + nxt + TILE_BYTES + j * 8192 + tid * 16);
      }
    }
    const char* kl = lds + cur;
    const char* vl = lds + cur + TILE_BYTES;

    // S^T = K' Q'^T over this wave's 32-key half
    f32x16 s;
#pragma unroll
    for (int r = 0; r < 16; ++r) s[r] = 0.f;
    __builtin_amdgcn_s_setprio(1);
#pragma unroll
    for (int kc = 0; kc < 8; ++kc) {
      f16x8 kf = *(const f16x8*)(kl + (ks * 32 + c) * 256 + ((kc * 32 + h * 16) ^ swz));
      s = __builtin_amdgcn_mfma_f32_32x32x16_f16(kf, qf[kc], s, 0, 0, 0);
    }
    __builtin_amdgcn_s_setprio(0);

    // lane-local online softmax (log2 domain; row q = c)
    float cm = s[0];
#pragma unroll
    for (int r = 1; r < 16; ++r) cm = fmaxf(cm, s[r]);
    cm = fmaxf(cm, __shfl_xor(cm, 32));
    if (__any(cm > m_run + 11.0f)) {  // defer-max: rescale only on real growth
      const float mn = fmaxf(m_run, cm);
      const float al = EXP2(m_run - mn);
      m_run = mn;
      l_run *= al;
#pragma unroll
      for (int d = 0; d < 4; ++d) {
#pragma unroll
        for (int r = 0; r < 16; ++r) acc[d][r] *= al;
      }
    }
    float ps = 0.f;
#pragma unroll
    for (int r = 0; r < 16; ++r) {
      s[r] = EXP2(s[r] - m_run);
      ps += s[r];
    }
    l_run += ps;

    // PV: O^T += V^T P^T over the wave's two local 16-key chunks
#pragma unroll
    for (int kc = 0; kc < 2; ++kc) {
      const int A = kc * 8;
      const int Bb = A + 4;
      unsigned pA0 = pk2(s[A + 0], s[A + 1]);
      unsigned pA1 = pk2(s[A + 2], s[A + 3]);
      unsigned pB0 = pk2(s[Bb + 0], s[Bb + 1]);
      unsigned pB1 = pk2(s[Bb + 2], s[Bb + 3]);
      unsigned own0 = h ? pB0 : pA0;
      unsigned own1 = h ? pB1 : pA1;
      unsigned snd0 = h ? pA0 : pB0;
      unsigned snd1 = h ? pA1 : pB1;
      unsigned rcv0 = __shfl_xor(snd0, 32);
      unsigned rcv1 = __shfl_xor(snd1, 32);
      u32x4 pw;
      pw[0] = h ? rcv0 : own0;  // elems 0,1 (source half h=0)
      pw[1] = h ? rcv1 : own1;  // elems 2,3
      pw[2] = h ? own0 : rcv0;  // elems 4,5 (source half h=1)
      pw[3] = h ? own1 : rcv1;  // elems 6,7
      f16x8 pf = __builtin_bit_cast(f16x8, pw);
      const int kci = ks * 2 + kc;  // global 16-key chunk in tile
      __builtin_amdgcn_s_setprio(1);
#pragma unroll
      for (int d = 0; d < 4; ++d) {
        f16x8 vf = *(const f16x8*)(vl + (d * 32 + c) * 128 + ((kci * 32 + h * 16) ^ swz));
        acc[d] = __builtin_amdgcn_mfma_f32_32x32x16_f16(vf, pf, acc[d], 0, 0, 0);
      }
      __builtin_amdgcn_s_setprio(0);
    }
  }

  // ---- epilogue: merge the two key-half partials, transpose, store ----
  l_run += __shfl_xor(l_run, 32);  // full half-range sum for row q=c

  __syncthreads();  // all waves done with stage buffers
  float2* ml = (float2*)(lds + 65536);
  if (h == 0) ml[wid * 32 + c] = make_float2(m_run, l_run);
  __syncthreads();
  const float2 po = ml[(wid ^ 1) * 32 + c];  // partner key-half (same qs)
  const float ms = fmaxf(m_run, po.x);
  const float lstar = l_run * EXP2(m_run - ms) + po.y * EXP2(po.x - ms);
  const float w = EXP2(m_run - ms) / lstar;

  char* T = lds;  // 128 q x 128 d fp32 (64KB), swizzled rows
  if (ks == 0) {
#pragma unroll
    for (int d = 0; d < 4; ++d) {
#pragma unroll
      for (int rr = 0; rr < 4; ++rr) {
        const int dd = d * 32 + rr * 8 + h * 4;
        float4 v4;
        v4.x = acc[d][rr * 4 + 0] * w;
        v4.y = acc[d][rr * 4 + 1] * w;
        v4.z = acc[d][rr * 4 + 2] * w;
        v4.w = acc[d][rr * 4 + 3] * w;
        *(float4*)(T + (qs * 32 + c) * 512 + ((dd * 4) ^ swz)) = v4;
      }
    }
  }
  __syncthreads();
  if (ks == 1) {
#pragma unroll
    for (int d = 0; d < 4; ++d) {
#pragma unroll
      for (int rr = 0; rr < 4; ++rr) {
        const int dd = d * 32 + rr * 8 + h * 4;
        float4* p = (float4*)(T + (qs * 32 + c) * 512 + ((dd * 4) ^ swz));
        float4 t = *p;
        t.x += acc[d][rr * 4 + 0] * w;
        t.y += acc[d][rr * 4 + 1] * w;
        t.z += acc[d][rr * 4 + 2] * w;
        t.w += acc[d][rr * 4 + 3] * w;
        *p = t;
      }
    }
  }
  __syncthreads();

  float* obase = out + ((size_t)bq * S_LEN + qt * 128) * DD;
#pragma unroll
  for (int p = 0; p < 8; ++p) {
    const int idx = p * 512 + tid;
    const int q = idx >> 5;
    const int d0 = (idx & 31) * 4;
    float4 v4 = *(const float4*)(T + q * 512 + ((d0 * 4) ^ ((q & 7) << 4)));
    *(float4*)(obase + q * DD + d0) = v4;
  }
}

// --------------------------- launcher ------------------------------------
extern "C" void kernel_launch(void* const* d_in, const int* in_sizes, int n_in,
                              void* d_out, int out_size, void* d_ws, size_t ws_size,
                              hipStream_t stream) {
  const float* Q = (const float*)d_in[0];
  const float* K = (const float*)d_in[1];
  const float* V = (const float*)d_in[2];
  const float* pq = (const float*)d_in[3];
  const float* pk = (const float*)d_in[4];
  float* out = (float*)d_out;
  char* ws = (char*)d_ws;
  char* qh = ws;                         // 8 MB fp16 scaled Q (log2e folded)
  char* kimg = ws + (8u << 20);          // 8 MB K image (gated, swizzled)
  char* vimg = ws + (16u << 20);         // 8 MB V image (transposed, swizzled)

  prep_q_k<<<2048, 256, 0, stream>>>(Q, pq, qh);
  prep_kv<<<512, 256, 0, stream>>>(K, V, pk, kimg, vimg);
  attn_main<<<256, 512, 0, stream>>>(qh, kimg, vimg, out);
}